// Round 13
// baseline (35.667 us; speedup 1.0000x reference)
//
#include <hip/hip_runtime.h>
#include <hip/hip_fp16.h>

// Problem constants (from reference)
#define BSZ     1024   // batch
#define N_IN    1024
#define NLAYERS 5
#define NPL     2048   // nodes per layer
#define FANIN   16
#define N_OUT   256

#define VALS_ROWS   (N_IN + 4 * NPL)            // 9216 gatherable rows
#define CPB         4                           // batch columns per block
#define NBLK        (BSZ / CPB)                 // 256 blocks
#define ROW_B       8                           // 4 cols x fp16 per row
#define LDS_BYTES   (VALS_ROWS * ROW_B)         // 73728 B
#define L3_BASE     (N_IN + 3 * NPL)            // 7168: first layer-3 row

// d_ws layout (u32 units)
#define PK012_OFF   0            // [3*NPL][16]      layers 0..2, sorted+rotated
#define PK4_OFF     98304        // [N_OUT][16]      layer 4 (used nodes), raw idx
#define PK3C_OFF    102400       // [<=NPL][16]      layer 3 compacted, sorted+rotated
#define META3_OFF   135168       // [<=NPL]          (node_id << 16) | fp16(bias)
#define CNT3_OFF    137216       // 1 u32

union H4 { unsigned long long u; __half2 h2[2]; };

__device__ __forceinline__ float fast_tanh(float x) {
    float t = __expf(2.0f * x);
    return 1.0f - 2.0f / (t + 1.0f);
}
__device__ __forceinline__ float fast_sigmoid(float x) {
    return 1.0f / (1.0f + __expf(-x));
}

// ---------------------------------------------------------------------------
// Prep kernel, 25 blocks x 1024 threads.
// Blocks 1..24 (tid<256): pack layers 0..2 (6144 nodes): val =
//   ((idx*8) << 16) | fp16(w), per-node bank-sorted (key = idx&15 = the
//   ds_read_b64 bank-pair), rotated by n for near-uniform wave bank spread.
// Block 0: pack layer-4's 256 used nodes (raw idx); build layer-3 liveness
//   flags from their 4096 indices; ballot-based two-level prefix sum; emit
//   compacted pk3c[pos][16] (sorted, rotated by pos) + meta3[pos] =
//   (node_id << 16) | fp16(bias). cnt3 -> ws[CNT3_OFF].
// ---------------------------------------------------------------------------
__global__ __launch_bounds__(1024) void prep_kernel(
    const int* __restrict__ src, const float* __restrict__ wsrc,
    const float* __restrict__ biases, unsigned int* __restrict__ ws)
{
    const int tid = threadIdx.x;

    if (blockIdx.x != 0) {
        if (tid >= 256) return;
        const int t = (blockIdx.x - 1) * 256 + tid;   // node l*NPL+n, l<3
        const int n = t & (NPL - 1);
        const int*   s  = src  + (size_t)t * FANIN;
        const float* ww = wsrc + (size_t)t * FANIN;

        int          key[FANIN];
        unsigned int val[FANIN];
#pragma unroll
        for (int f = 0; f < FANIN; ++f) {
            unsigned int idx = (unsigned int)s[f];
            key[f] = (int)(idx & 15u);
            unsigned short hw = __half_as_ushort(__float2half(ww[f]));
            val[f] = ((idx << 3) << 16) | (unsigned int)hw;
        }
        unsigned int* dst = ws + PK012_OFF + (size_t)t * FANIN;
#pragma unroll
        for (int f = 0; f < FANIN; ++f) {
            int rank = 0;
#pragma unroll
            for (int g = 0; g < FANIN; ++g)
                rank += (key[g] < key[f]) || (key[g] == key[f] && g < f);
            dst[(rank - n) & 15] = val[f];
        }
        return;
    }

    // ---- block 0: layer-4 pack + layer-3 liveness/compaction ----
    __shared__ unsigned int flags[NPL];
    __shared__ unsigned int chunk_tot[32];
    __shared__ unsigned int chunk_excl[32];
    flags[tid] = 0u; flags[tid + 1024] = 0u;
    __syncthreads();

    const int base4 = (4 * NPL + (NPL - N_OUT)) * FANIN;  // first used L4 edge
#pragma unroll
    for (int e = tid; e < N_OUT * FANIN; e += 1024) {     // 4 iterations
        unsigned int idx = (unsigned int)src[base4 + e];
        unsigned short hw = __half_as_ushort(__float2half(wsrc[base4 + e]));
        ws[PK4_OFF + e] = (idx << 16) | (unsigned int)hw;
        if (idx >= (unsigned)L3_BASE) flags[idx - L3_BASE] = 1u;  // benign race
    }
    __syncthreads();

    // two-level ballot scan: wave wv owns chunks wv and wv+16 (64 nodes each)
    const int lane = tid & 63;
    const int wv   = tid >> 6;
    const int n0 = wv * 64 + lane;
    const int n1 = (wv + 16) * 64 + lane;
    const unsigned long long m0 = __ballot(flags[n0] != 0u);
    const unsigned long long m1 = __ballot(flags[n1] != 0u);
    if (lane == 0) {
        chunk_tot[wv]      = (unsigned int)__popcll(m0);
        chunk_tot[wv + 16] = (unsigned int)__popcll(m1);
    }
    __syncthreads();
    if (tid < 32) {
        unsigned int s = 0;
        for (int i = 0; i < 32; ++i) s += (i < tid) ? chunk_tot[i] : 0u;
        chunk_excl[tid] = s;
        if (tid == 31) ws[CNT3_OFF] = s + chunk_tot[31];
    }
    __syncthreads();

    const unsigned long long below = (1ull << lane) - 1ull;
    const unsigned int p0 = chunk_excl[wv]      + (unsigned int)__popcll(m0 & below);
    const unsigned int p1 = chunk_excl[wv + 16] + (unsigned int)__popcll(m1 & below);

#pragma unroll
    for (int k = 0; k < 2; ++k) {
        const int nn = k ? n1 : n0;
        const unsigned int pos = k ? p1 : p0;
        if (flags[nn]) {
            unsigned short hb = __half_as_ushort(
                __float2half(biases[(size_t)3 * NPL + nn]));
            ws[META3_OFF + pos] = ((unsigned int)nn << 16) | (unsigned int)hb;

            const int t3 = (3 * NPL + nn) * FANIN;
            int          key[FANIN];
            unsigned int val[FANIN];
#pragma unroll
            for (int f = 0; f < FANIN; ++f) {
                unsigned int idx = (unsigned int)src[t3 + f];
                key[f] = (int)(idx & 15u);
                unsigned short hw = __half_as_ushort(__float2half(wsrc[t3 + f]));
                val[f] = ((idx << 3) << 16) | (unsigned int)hw;
            }
            unsigned int* dst = ws + PK3C_OFF + (size_t)pos * FANIN;
#pragma unroll
            for (int f = 0; f < FANIN; ++f) {
                int rank = 0;
#pragma unroll
                for (int g = 0; g < FANIN; ++g)
                    rank += (key[g] < key[f]) || (key[g] == key[f] && g < f);
                dst[(rank - (int)pos) & 15] = val[f];
            }
        }
    }
}

// ---------------------------------------------------------------------------
// One node: 16 x {ds_read_b64 gather, broadcast w, 2 x v_pk_fma_f16},
// f32 tanh, one ds_write_b64 of the 4xfp16 activation row.
// ---------------------------------------------------------------------------
__device__ __forceinline__ void node_tanh_pk(
    const unsigned int* pk, __half hb, int row, char* lds)
{
    __half2 a01 = __halves2half2(hb, hb);
    __half2 a23 = a01;
#pragma unroll
    for (int f = 0; f < FANIN; ++f) {
        const unsigned int u = pk[f];
        H4 v;
        v.u = *reinterpret_cast<const unsigned long long*>(lds + (u >> 16));
        const __half2 w2 = __half2half2(
            __ushort_as_half((unsigned short)(u & 0xffffu)));
        a01 = __hfma2(v.h2[0], w2, a01);
        a23 = __hfma2(v.h2[1], w2, a23);
    }
    float a0 = fast_tanh(__half2float(__low2half(a01)));
    float a1 = fast_tanh(__half2float(__high2half(a01)));
    float a2 = fast_tanh(__half2float(__low2half(a23)));
    float a3 = fast_tanh(__half2float(__high2half(a23)));
    H4 rec;
    rec.h2[0] = __halves2half2(__float2half(a0), __float2half(a1));
    rec.h2[1] = __halves2half2(__float2half(a2), __float2half(a3));
    *reinterpret_cast<unsigned long long*>(lds + (size_t)row * ROW_B) = rec.u;
}

// ---------------------------------------------------------------------------
// Fused whole-network kernel (r10 structure for layers 0..2). Layer 3 runs
// only the compacted alive nodes (cnt3 ~ 735 < 1024 -> single sweep); per
// thread the only extra state is one meta u32 (dest node id + fp16 bias).
// Layer 4 computes the 256 output-reachable nodes in f32 and writes d_out.
// ---------------------------------------------------------------------------
__global__ __launch_bounds__(1024) void fused_net_kernel(
    const float* __restrict__ inputs,           // (BSZ, N_IN) f32
    const unsigned int* __restrict__ ws,        // prep output
    const float* __restrict__ biases,           // (L, NPL) f32
    float* __restrict__ out)                    // (BSZ, N_OUT) f32
{
    extern __shared__ char lds[];
    const int tid = threadIdx.x;
    const int c0  = blockIdx.x * CPB;           // batch base for this block
    const unsigned int* pk012 = ws + PK012_OFF;
    const unsigned int* pk3c  = ws + PK3C_OFF;
    const unsigned int* pk4   = ws + PK4_OFF;
    const unsigned int* meta3 = ws + META3_OFF;
    const int cnt3 = (int)ws[CNT3_OFF];         // uniform

    // ---- stage 4 input columns as one 8-B row record per node ----
    {
        float v0 = inputs[(size_t)(c0 + 0) * N_IN + tid];
        float v1 = inputs[(size_t)(c0 + 1) * N_IN + tid];
        float v2 = inputs[(size_t)(c0 + 2) * N_IN + tid];
        float v3 = inputs[(size_t)(c0 + 3) * N_IN + tid];
        H4 rec;
        rec.h2[0] = __halves2half2(__float2half(v0), __float2half(v1));
        rec.h2[1] = __halves2half2(__float2half(v2), __float2half(v3));
        *reinterpret_cast<unsigned long long*>(lds + (size_t)tid * ROW_B) = rec.u;
    }

    unsigned int pkA[FANIN], pkB[FANIN];
    unsigned int mA = 0;

    // preload layer 0, sweep 0 (overlaps input staging + barrier)
#pragma unroll
    for (int f = 0; f < FANIN; ++f)
        pkA[f] = pk012[(size_t)tid * FANIN + f];

    __syncthreads();

    // ---- layers 0..2: full 2048 nodes, 2 sweeps, tanh ----
    for (int l = 0; l < 3; ++l) {
        const float* bl = biases + (size_t)l * NPL;
        const int wbase = N_IN + l * NPL;

        // issue sweep-1 pk loads before sweep-0 compute
#pragma unroll
        for (int f = 0; f < FANIN; ++f)
            pkB[f] = pk012[((size_t)l * NPL + 1024 + tid) * FANIN + f];

        node_tanh_pk(pkA, __float2half(bl[tid]), wbase + tid, lds);

        // prefetch next work for pkA before the barrier
        if (l < 2) {
#pragma unroll
            for (int f = 0; f < FANIN; ++f)
                pkA[f] = pk012[((size_t)(l + 1) * NPL + tid) * FANIN + f];
        } else if (tid < cnt3) {                // layer-3 compacted stream
            mA = meta3[tid];
#pragma unroll
            for (int f = 0; f < FANIN; ++f)
                pkA[f] = pk3c[(size_t)tid * FANIN + f];
        }

        node_tanh_pk(pkB, __float2half(bl[1024 + tid]), wbase + 1024 + tid, lds);
        __syncthreads();
    }

    // ---- layer 3: compacted alive nodes (cnt3 ~ 735 -> one sweep) ----
    if (cnt3 > 1024 && 1024 + tid < cnt3) {     // dead in practice; correct always
        const unsigned int mB = meta3[1024 + tid];
#pragma unroll
        for (int f = 0; f < FANIN; ++f)
            pkB[f] = pk3c[(size_t)(1024 + tid) * FANIN + f];
        if (tid < cnt3)
            node_tanh_pk(pkA, __ushort_as_half((unsigned short)(mA & 0xffffu)),
                         L3_BASE + (int)(mA >> 16), lds);
        node_tanh_pk(pkB, __ushort_as_half((unsigned short)(mB & 0xffffu)),
                     L3_BASE + (int)(mB >> 16), lds);
    } else if (tid < cnt3) {
        node_tanh_pk(pkA, __ushort_as_half((unsigned short)(mA & 0xffffu)),
                     L3_BASE + (int)(mA >> 16), lds);
    }

    // prefetch layer-4 pk (pkA consumed above; hides under barrier drain)
    if (tid < N_OUT) {
#pragma unroll
        for (int f = 0; f < FANIN; ++f)
            pkB[f] = pk4[(size_t)tid * FANIN + f];
    }
    __syncthreads();

    // ---- layer 4: last N_OUT nodes only; f32 accum; sigmoid; f32 out ----
    if (tid < N_OUT) {
        const float bv = biases[(size_t)4 * NPL + (NPL - N_OUT) + tid];
        float a0 = bv, a1 = bv, a2 = bv, a3 = bv;
#pragma unroll
        for (int f = 0; f < FANIN; ++f) {
            const unsigned int u   = pkB[f];
            const unsigned int off = (u >> 16) << 3;     // raw idx -> byte off
            H4 v;
            v.u = *reinterpret_cast<const unsigned long long*>(lds + off);
            const float wf = __half2float(
                __ushort_as_half((unsigned short)(u & 0xffffu)));
            a0 = fmaf(__half2float(v.h2[0].x), wf, a0);
            a1 = fmaf(__half2float(v.h2[0].y), wf, a1);
            a2 = fmaf(__half2float(v.h2[1].x), wf, a2);
            a3 = fmaf(__half2float(v.h2[1].y), wf, a3);
        }
        a0 = fast_sigmoid(a0); a1 = fast_sigmoid(a1);
        a2 = fast_sigmoid(a2); a3 = fast_sigmoid(a3);
        const int j = tid;                               // output column
        out[(size_t)(c0 + 0) * N_OUT + j] = a0;
        out[(size_t)(c0 + 1) * N_OUT + j] = a1;
        out[(size_t)(c0 + 2) * N_OUT + j] = a2;
        out[(size_t)(c0 + 3) * N_OUT + j] = a3;
    }
}

// ---------------------------------------------------------------------------
// Launch: prep (pack + ballot-scan layer-3 compaction) then one fused kernel.
// 256 blocks x 1024 threads, 73728 B dynamic LDS per block.
// ---------------------------------------------------------------------------
extern "C" void kernel_launch(void* const* d_in, const int* in_sizes, int n_in,
                              void* d_out, int out_size, void* d_ws, size_t ws_size,
                              hipStream_t stream)
{
    const float* inputs   = (const float*)d_in[0];
    const int*   edge_src = (const int*)  d_in[1];
    const float* edge_w   = (const float*)d_in[2];
    const float* biases   = (const float*)d_in[3];
    float* out = (float*)d_out;
    unsigned int* ws = (unsigned int*)d_ws;     // ~550 KB used

    prep_kernel<<<25, 1024, 0, stream>>>(edge_src, edge_w, biases, ws);

    fused_net_kernel<<<NBLK, 1024, LDS_BYTES, stream>>>(
        inputs, ws, biases, out);
}

// Round 14
// 25.932 us; speedup vs baseline: 1.3754x; 1.3754x over previous
//
#include <hip/hip_runtime.h>
#include <hip/hip_fp16.h>

// Problem constants (from reference)
#define BSZ     1024   // batch
#define N_IN    1024
#define NLAYERS 5
#define NPL     2048   // nodes per layer
#define FANIN   16
#define N_OUT   256

#define VALS_ROWS   (N_IN + 4 * NPL)            // 9216 gatherable rows
#define CPB         4                           // batch columns per block
#define NBLK        (BSZ / CPB)                 // 256 blocks
#define ROW_B       8                           // 4 cols x fp16 per row
#define LDS_BYTES   (VALS_ROWS * ROW_B)         // 73728 B

union H4 { unsigned long long u; __half2 h2[2]; };

// ---------------------------------------------------------------------------
// Pack kernel. Layout [l*NPL+n][FANIN] (lane-local 64B -> dwordx4 loads).
// Per node: sort its 16 edges by LDS bank-pair (idx & 15) via static-index
// rank computation, then store rotated by n: slot f holds the rank-((f+n)&15)
// edge. At gather step f, the 64 lanes of a wave (consecutive n) present each
// rank exactly 4x -> near-uniform bank spread. Sum-order change is harmless.
// val = (off_hi << 16) | fp16(w); off_hi = idx*8 (pre-shifted byte offset,
// fits 16 bits since tanh layers gather idx < 7168) or raw idx for layer 4.
// ---------------------------------------------------------------------------
__global__ __launch_bounds__(256) void pack_edges_kernel(
    const int* __restrict__ src, const float* __restrict__ wsrc,
    unsigned int* __restrict__ packed)
{
    int t = blockIdx.x * 256 + threadIdx.x;      // one (l, n) pair per thread
    if (t >= NLAYERS * NPL) return;
    const int l = t / NPL;
    const int n = t - l * NPL;
    const int*   s  = src  + (size_t)t * FANIN;
    const float* ww = wsrc + (size_t)t * FANIN;

    int          key[FANIN];
    unsigned int val[FANIN];
#pragma unroll
    for (int f = 0; f < FANIN; ++f) {
        unsigned int idx = (unsigned int)s[f];
        key[f] = (int)(idx & 15u);                       // bank-pair of ds_read_b64
        unsigned int hi = (l < NLAYERS - 1) ? (idx << 3) // pre-shifted byte offset
                                            : idx;       // final layer: raw idx
        unsigned short hw = __half_as_ushort(__float2half(ww[f]));
        val[f] = (hi << 16) | (unsigned int)hw;
    }

    unsigned int* dst = packed + (size_t)t * FANIN;
#pragma unroll
    for (int f = 0; f < FANIN; ++f) {
        int rank = 0;
#pragma unroll
        for (int g = 0; g < FANIN; ++g)
            rank += (key[g] < key[f]) || (key[g] == key[f] && g < f);
        dst[(rank - n) & 15] = val[f];                   // rotated sorted order
    }
}

// ---------------------------------------------------------------------------
// Fused whole-network kernel. Each block owns 4 batch columns; all
// activations live in LDS as 8-B rows [row][4 x fp16]; every gather is one
// ds_read_b64 with the bank-balanced schedule. pk double-buffered (pkA/pkB):
// next sweep's loads issue before the current sweep's compute, next layer's
// before the barrier, so L2 latency hides under FMA + LDS work. One
// __syncthreads per layer. Layer 4 computes only the 256 output-reachable
// nodes (f32 accumulation) and writes d_out directly.
// ---------------------------------------------------------------------------
__device__ __forceinline__ float fast_tanh(float x) {
    float t = __expf(2.0f * x);
    return 1.0f - 2.0f / (t + 1.0f);
}
__device__ __forceinline__ float fast_sigmoid(float x) {
    return 1.0f / (1.0f + __expf(-x));
}

__device__ __forceinline__ void node_tanh(
    const unsigned int* pk, float bvf, int row, char* lds)
{
    float a0 = bvf, a1 = bvf, a2 = bvf, a3 = bvf;
#pragma unroll
    for (int f = 0; f < FANIN; ++f) {
        const unsigned int u   = pk[f];
        const unsigned int off = u >> 16;                // pre-shifted byte off
        H4 v;
        v.u = *reinterpret_cast<const unsigned long long*>(lds + off);
        const float wf = __half2float(
            __ushort_as_half((unsigned short)(u & 0xffffu)));
        a0 = fmaf(__half2float(v.h2[0].x), wf, a0);
        a1 = fmaf(__half2float(v.h2[0].y), wf, a1);
        a2 = fmaf(__half2float(v.h2[1].x), wf, a2);
        a3 = fmaf(__half2float(v.h2[1].y), wf, a3);
    }
    a0 = fast_tanh(a0); a1 = fast_tanh(a1);
    a2 = fast_tanh(a2); a3 = fast_tanh(a3);
    H4 rec;
    rec.h2[0] = __halves2half2(__float2half(a0), __float2half(a1));
    rec.h2[1] = __halves2half2(__float2half(a2), __float2half(a3));
    *reinterpret_cast<unsigned long long*>(lds + (size_t)row * ROW_B) = rec.u;
}

__global__ __launch_bounds__(1024) void fused_net_kernel(
    const float* __restrict__ inputs,           // (BSZ, N_IN) f32
    const unsigned int* __restrict__ packed,    // [l*NPL+n][FANIN]
    const float* __restrict__ biases,           // (L, NPL) f32
    float* __restrict__ out)                    // (BSZ, N_OUT) f32
{
    extern __shared__ char lds[];
    const int tid = threadIdx.x;
    const int c0  = blockIdx.x * CPB;           // batch base for this block

    // ---- stage 4 input columns as one 8-B row record per node ----
    {
        float v0 = inputs[(size_t)(c0 + 0) * N_IN + tid];
        float v1 = inputs[(size_t)(c0 + 1) * N_IN + tid];
        float v2 = inputs[(size_t)(c0 + 2) * N_IN + tid];
        float v3 = inputs[(size_t)(c0 + 3) * N_IN + tid];
        H4 rec;
        rec.h2[0] = __halves2half2(__float2half(v0), __float2half(v1));
        rec.h2[1] = __halves2half2(__float2half(v2), __float2half(v3));
        *reinterpret_cast<unsigned long long*>(lds + (size_t)tid * ROW_B) = rec.u;
    }
    __syncthreads();

    unsigned int pkA[FANIN], pkB[FANIN];

    // preload layer 0, sweep 0
#pragma unroll
    for (int f = 0; f < FANIN; ++f)
        pkA[f] = packed[(size_t)tid * FANIN + f];

    for (int l = 0; l < NLAYERS - 1; ++l) {
        const float* bl = biases + (size_t)l * NPL;
        const int wbase = N_IN + l * NPL;

        // issue sweep-1 pk loads before sweep-0 compute
#pragma unroll
        for (int f = 0; f < FANIN; ++f)
            pkB[f] = packed[((size_t)l * NPL + 1024 + tid) * FANIN + f];

        node_tanh(pkA, bl[tid], wbase + tid, lds);

        // issue NEXT-layer sweep-0 pk loads (or final-layer pk) before the
        // barrier: latency hides under sweep-1 compute + barrier drain
        if (l < NLAYERS - 2) {
#pragma unroll
            for (int f = 0; f < FANIN; ++f)
                pkA[f] = packed[((size_t)(l + 1) * NPL + tid) * FANIN + f];
        } else if (tid < N_OUT) {
            const int n4 = NPL - N_OUT + tid;
#pragma unroll
            for (int f = 0; f < FANIN; ++f)
                pkA[f] = packed[((size_t)(NLAYERS - 1) * NPL + n4) * FANIN + f];
        }

        node_tanh(pkB, bl[1024 + tid], wbase + 1024 + tid, lds);
        __syncthreads();
    }

    // ---- layer 4: last N_OUT nodes only; f32 accum; sigmoid; f32 out ----
    if (tid < N_OUT) {
        const int n = NPL - N_OUT + tid;
        const float bv = biases[(size_t)(NLAYERS - 1) * NPL + n];
        float a0 = bv, a1 = bv, a2 = bv, a3 = bv;
#pragma unroll
        for (int f = 0; f < FANIN; ++f) {
            const unsigned int u   = pkA[f];
            const unsigned int off = (u >> 16) << 3;     // raw idx -> byte off
            H4 v;
            v.u = *reinterpret_cast<const unsigned long long*>(lds + off);
            const float wf = __half2float(
                __ushort_as_half((unsigned short)(u & 0xffffu)));
            a0 = fmaf(__half2float(v.h2[0].x), wf, a0);
            a1 = fmaf(__half2float(v.h2[0].y), wf, a1);
            a2 = fmaf(__half2float(v.h2[1].x), wf, a2);
            a3 = fmaf(__half2float(v.h2[1].y), wf, a3);
        }
        a0 = fast_sigmoid(a0); a1 = fast_sigmoid(a1);
        a2 = fast_sigmoid(a2); a3 = fast_sigmoid(a3);
        const int j = tid;                               // output column
        out[(size_t)(c0 + 0) * N_OUT + j] = a0;
        out[(size_t)(c0 + 1) * N_OUT + j] = a1;
        out[(size_t)(c0 + 2) * N_OUT + j] = a2;
        out[(size_t)(c0 + 3) * N_OUT + j] = a3;
    }
}

// ---------------------------------------------------------------------------
// Launch: pack (sort+rotate) edges into d_ws (0.66 MB), then one fused kernel.
// 256 blocks x 1024 threads, 73728 B dynamic LDS per block.
// ---------------------------------------------------------------------------
extern "C" void kernel_launch(void* const* d_in, const int* in_sizes, int n_in,
                              void* d_out, int out_size, void* d_ws, size_t ws_size,
                              hipStream_t stream)
{
    const float* inputs   = (const float*)d_in[0];
    const int*   edge_src = (const int*)  d_in[1];
    const float* edge_w   = (const float*)d_in[2];
    const float* biases   = (const float*)d_in[3];
    float* out = (float*)d_out;
    unsigned int* packed = (unsigned int*)d_ws;   // L*NPL*FANIN*4 B = 655,360 B

    pack_edges_kernel<<<(NLAYERS * NPL + 255) / 256, 256, 0, stream>>>(
        edge_src, edge_w, packed);

    fused_net_kernel<<<NBLK, 1024, LDS_BYTES, stream>>>(
        inputs, packed, biases, out);
}